// Round 13
// baseline (55.168 us; speedup 1.0000x reference)
//
#include <hip/hip_runtime.h>

#define BATCH  8
#define NPTS   4096
#define TPB    256
#define QPT    16                   // queries per thread -> whole batch per block
#define NSEG   64
#define SEG    (NPTS / NSEG)        // 64 ref points per block
#define CLOUD  (BATCH * NPTS)       // 32768 points per cloud
#define QTOTAL (2 * CLOUD)          // 65536 outputs
#define NBLK   (2 * BATCH * NSEG)   // 1024 blocks

// ws layout: [pre: 65536 * 16 B = 1 MB][part: 16 dirb * 64 seg * 4096 * 4 B = 16 MB]
#define PART_OFF_FLOATS (QTOTAL * 4)

// Per-point preprocess: (x,y,z) -> (-2x, -2y, -2z, w = x^2+y^2+z^2).
__global__ __launch_bounds__(TPB) void nnd_prep(const float* __restrict__ xyz1,
                                                const float* __restrict__ xyz2,
                                                float4* __restrict__ pre) {
    int i = blockIdx.x * TPB + (int)threadIdx.x;       // 0..65535
    const float* src = (i < CLOUD) ? xyz1 : xyz2;
    int j = (i < CLOUD) ? i : i - CLOUD;
    float x = src[3 * j + 0], y = src[3 * j + 1], z = src[3 * j + 2];
    pre[i] = make_float4(-2.f * x, -2.f * y, -2.f * z, x * x + y * y + z * z);
}

// Main: block = (dir, b, segment of 64 ref points); thread owns 16 queries.
// Per ref point per query: e = fma(-2zr,qz,wr); fma(-2yr,qy,·); fma(-2xr,qx,·)
// = 3 VALU; point-pairs fold via fmin(fmin) -> v_min3 = 0.5 VALU. ||q||^2 is
// added ONCE at the end (min is invariant to the per-query constant).
__global__ __launch_bounds__(TPB, 4) void nnd_main(const float* __restrict__ xyz1,
                                                   const float* __restrict__ xyz2,
                                                   const float4* __restrict__ pre,
                                                   float* __restrict__ part) {
    // Bijective XCD swizzle (1024 = 8*128): contiguous logical slab per XCD
    // -> each XCD works 2 (dir,b) slices; ~1.5 MB working set, L2-resident.
    int bid = ((int)blockIdx.x & 7) * (NBLK / 8) + ((int)blockIdx.x >> 3);
    const int seg = bid & (NSEG - 1);             // 6 bits
    const int b   = (bid >> 6) & (BATCH - 1);     // 3 bits
    const int dir = bid >> 9;                     // 1 bit

    __shared__ float4 s[SEG];                     // 1 KB

    if ((int)threadIdx.x < SEG)
        s[threadIdx.x] = pre[(size_t)(dir == 0 ? 1 : 0) * CLOUD
                             + (size_t)b * NPTS + (size_t)seg * SEG + threadIdx.x];

    // 16 consecutive queries per thread: 48 floats = 12 aligned float4 loads.
    const float* q = (dir == 0) ? xyz1 : xyz2;
    const int n0 = (int)threadIdx.x * QPT;
    const float4* qv = (const float4*)(q + ((size_t)b * NPTS + n0) * 3);
    float qf[48];
    #pragma unroll
    for (int v = 0; v < 12; ++v) {
        float4 t = qv[v];
        qf[4 * v + 0] = t.x; qf[4 * v + 1] = t.y;
        qf[4 * v + 2] = t.z; qf[4 * v + 3] = t.w;
    }
    float qx[QPT], qy[QPT], qz[QPT];
    #pragma unroll
    for (int k = 0; k < QPT; ++k) {
        qx[k] = qf[3 * k]; qy[k] = qf[3 * k + 1]; qz[k] = qf[3 * k + 2];
    }

    float best[QPT];
    #pragma unroll
    for (int k = 0; k < QPT; ++k) best[k] = 1e30f;

    __syncthreads();

    #pragma unroll 2
    for (int p = 0; p < SEG; p += 2) {
        float4 A0 = s[p];                          // broadcast ds_read_b128
        float4 A1 = s[p + 1];
        #pragma unroll
        for (int k = 0; k < QPT; ++k) {
            float e0 = fmaf(A0.z, qz[k], A0.w);
            e0 = fmaf(A0.y, qy[k], e0);
            e0 = fmaf(A0.x, qx[k], e0);
            float e1 = fmaf(A1.z, qz[k], A1.w);
            e1 = fmaf(A1.y, qy[k], e1);
            e1 = fmaf(A1.x, qx[k], e1);
            best[k] = fminf(best[k], fminf(e0, e1));   // -> v_min3
        }
    }

    // Add ||q||^2 once; 4 coalesced float4 stores.
    float* dst = part + ((size_t)(dir * BATCH + b) * NSEG + seg) * NPTS + n0;
    #pragma unroll
    for (int v = 0; v < 4; ++v) {
        float4 r;
        #pragma unroll
        for (int u = 0; u < 4; ++u) {
            int k = 4 * v + u;
            float sqq = fmaf(qx[k], qx[k], fmaf(qy[k], qy[k], qz[k] * qz[k]));
            ((float*)&r)[u] = best[k] + sqq;
        }
        *(float4*)(dst + 4 * v) = r;
    }
}

// Fold the NSEG partials per query (coalesced within each segment row).
__global__ __launch_bounds__(TPB) void nnd_reduce(const float* __restrict__ part,
                                                  float* __restrict__ out) {
    int qid = blockIdx.x * TPB + (int)threadIdx.x;    // 0..65535
    int db = qid >> 12;                               // dir*BATCH+b
    int n  = qid & (NPTS - 1);
    const float* p = part + (size_t)db * NSEG * NPTS + n;
    float m = p[0];
    #pragma unroll 8
    for (int sgm = 1; sgm < NSEG; ++sgm) m = fminf(m, p[(size_t)sgm * NPTS]);
    out[qid] = m;
}

extern "C" void kernel_launch(void* const* d_in, const int* in_sizes, int n_in,
                              void* d_out, int out_size, void* d_ws, size_t ws_size,
                              hipStream_t stream) {
    const float* xyz1 = (const float*)d_in[0];
    const float* xyz2 = (const float*)d_in[1];
    float4* pre  = (float4*)d_ws;
    float*  part = (float*)d_ws + PART_OFF_FLOATS;
    float*  out  = (float*)d_out;

    nnd_prep<<<QTOTAL / TPB, TPB, 0, stream>>>(xyz1, xyz2, pre);
    nnd_main<<<NBLK, TPB, 0, stream>>>(xyz1, xyz2, pre, part);
    nnd_reduce<<<QTOTAL / TPB, TPB, 0, stream>>>(part, out);
}